// Round 2
// baseline (1687.704 us; speedup 1.0000x reference)
//
#include <hip/hip_runtime.h>

// Problem constants
#define B_SZ   64
#define S_LEN  200
#define H_DIM  1024
#define NHEAD  16
#define HDIM   64
#define FF_DIM 4096
#define NROWS  (B_SZ * S_LEN)   // 12800

typedef __bf16 bf16x8 __attribute__((ext_vector_type(8)));
typedef float  f32x4  __attribute__((ext_vector_type(4)));

__device__ __forceinline__ float b2f(ushort u) {
  return __uint_as_float(((unsigned int)u) << 16);
}
__device__ __forceinline__ ushort f2b(float f) {
  unsigned int u = __float_as_uint(f);
  u += 0x7fffu + ((u >> 16) & 1u);   // RNE
  return (ushort)(u >> 16);
}

// ---------------------------------------------------------------------------
// Transpose fp32 [K,N] -> bf16 [N,K]
// ---------------------------------------------------------------------------
__global__ __launch_bounds__(256) void transpose_to_bf16(
    const float* __restrict__ w, ushort* __restrict__ wt, int K, int N) {
  __shared__ float tile[32][33];
  int nb = blockIdx.x * 32, kb = blockIdx.y * 32;
  int tx = threadIdx.x, ty = threadIdx.y;  // 32 x 8
#pragma unroll
  for (int i = 0; i < 4; ++i) {
    int k = kb + ty + i * 8;
    tile[ty + i * 8][tx] = w[(size_t)k * N + nb + tx];
  }
  __syncthreads();
#pragma unroll
  for (int i = 0; i < 4; ++i) {
    int n = nb + ty + i * 8;
    wt[(size_t)n * K + kb + tx] = f2b(tile[tx][ty + i * 8]);
  }
}

// ---------------------------------------------------------------------------
// Concat 3 biases of 1024 into one 3072 vector
// ---------------------------------------------------------------------------
__global__ void concat_bias(const float* __restrict__ bq, const float* __restrict__ bk,
                            const float* __restrict__ bv, float* __restrict__ o) {
  int i = blockIdx.x * 256 + threadIdx.x;
  if (i < 1024) o[i] = bq[i];
  else if (i < 2048) o[i] = bk[i - 1024];
  else if (i < 3072) o[i] = bv[i - 2048];
}

// ---------------------------------------------------------------------------
// LayerNorm (fp32 in) -> bf16 out.  HAS_TIME: += time[r]*wt[c] + bt[c]
// One block (256 thr) per row of 1024.
// ---------------------------------------------------------------------------
template <int HAS_TIME>
__global__ __launch_bounds__(256) void ln_kernel(
    const float* __restrict__ x, const float* __restrict__ g, const float* __restrict__ be,
    const float* __restrict__ tv, const float* __restrict__ wt, const float* __restrict__ bt,
    ushort* __restrict__ out) {
  int r = blockIdx.x, t = threadIdx.x;
  const float4* xr = (const float4*)(x + (size_t)r * H_DIM);
  float4 xv = xr[t];
  float s  = xv.x + xv.y + xv.z + xv.w;
  float s2 = xv.x * xv.x + xv.y * xv.y + xv.z * xv.z + xv.w * xv.w;
#pragma unroll
  for (int off = 32; off; off >>= 1) {
    s  += __shfl_xor(s, off);
    s2 += __shfl_xor(s2, off);
  }
  __shared__ float red[8];
  int lane = t & 63, wid = t >> 6;
  if (lane == 0) { red[wid] = s; red[4 + wid] = s2; }
  __syncthreads();
  float S  = red[0] + red[1] + red[2] + red[3];
  float S2 = red[4] + red[5] + red[6] + red[7];
  float m    = S * (1.0f / H_DIM);
  float var  = S2 * (1.0f / H_DIM) - m * m;
  float rstd = rsqrtf(var + 1e-5f);
  float tval = HAS_TIME ? tv[r] : 0.0f;
  float4 gv = ((const float4*)g)[t];
  float4 bv = ((const float4*)be)[t];
  float v0 = (xv.x - m) * rstd * gv.x + bv.x;
  float v1 = (xv.y - m) * rstd * gv.y + bv.y;
  float v2 = (xv.z - m) * rstd * gv.z + bv.z;
  float v3 = (xv.w - m) * rstd * gv.w + bv.w;
  if (HAS_TIME) {
    float4 wv = ((const float4*)wt)[t];
    float4 btv = ((const float4*)bt)[t];
    v0 += tval * wv.x + btv.x;
    v1 += tval * wv.y + btv.y;
    v2 += tval * wv.z + btv.z;
    v3 += tval * wv.w + btv.w;
  }
  ushort4 o;
  o.x = f2b(v0); o.y = f2b(v1); o.z = f2b(v2); o.w = f2b(v3);
  ((ushort4*)(out + (size_t)r * H_DIM))[t] = o;
}

// ---------------------------------------------------------------------------
// bf16 MFMA GEMM: C[M,N] = A[M,K] * Bt[N,K]^T + bias[N]  (+ epilogue)
// EPI 0: bf16 out.  EPI 1: exact GELU -> bf16.  EPI 2: +resid -> fp32 out
//   (safe when Cv == resid: per-thread read-then-write of the same idx).
// 128x128 tile, BK=32, 256 threads (4 waves 2x2), mfma_f32_16x16x32_bf16.
// M%128==0, N%128==0, K%32==0 (guaranteed by our shapes).
// ---------------------------------------------------------------------------
template <int EPI>
__global__ __launch_bounds__(256) void gemm_bt(
    const ushort* __restrict__ A, const ushort* __restrict__ Bt,
    const float* __restrict__ bias, void* __restrict__ Cv,
    const float* __restrict__ resid, int M, int N, int K) {
  __shared__ __align__(16) ushort As[128][40];
  __shared__ __align__(16) ushort Bs[128][40];
  int t = threadIdx.x;
  int lane = t & 63, wave = t >> 6;
  int wm = wave >> 1, wn = wave & 1;
  int r15 = lane & 15, quad = lane >> 4;
  size_t row0 = (size_t)blockIdx.y * 128;
  size_t col0 = (size_t)blockIdx.x * 128;
  f32x4 acc[4][4] = {};

  for (int k0 = 0; k0 < K; k0 += 32) {
#pragma unroll
    for (int u = 0; u < 2; ++u) {
      int c = u * 256 + t;
      int row = c >> 2, cc = (c & 3) * 8;
      *(uint4*)&As[row][cc] = *(const uint4*)&A[(row0 + row) * K + k0 + cc];
      *(uint4*)&Bs[row][cc] = *(const uint4*)&Bt[(col0 + row) * K + k0 + cc];
    }
    __syncthreads();
    bf16x8 af[4], bfr[4];
#pragma unroll
    for (int i = 0; i < 4; ++i)
      af[i] = *(const bf16x8*)&As[wm * 64 + i * 16 + r15][quad * 8];
#pragma unroll
    for (int j = 0; j < 4; ++j)
      bfr[j] = *(const bf16x8*)&Bs[wn * 64 + j * 16 + r15][quad * 8];
#pragma unroll
    for (int i = 0; i < 4; ++i)
#pragma unroll
      for (int j = 0; j < 4; ++j)
        acc[i][j] = __builtin_amdgcn_mfma_f32_16x16x32_bf16(af[i], bfr[j], acc[i][j], 0, 0, 0);
    __syncthreads();
  }

  int mbase = (int)row0 + wm * 64;
  int nbase = (int)col0 + wn * 64;
#pragma unroll
  for (int i = 0; i < 4; ++i) {
#pragma unroll
    for (int j = 0; j < 4; ++j) {
      int col = nbase + j * 16 + r15;
      float bb = bias[col];
#pragma unroll
      for (int ii = 0; ii < 4; ++ii) {
        int row = mbase + i * 16 + quad * 4 + ii;
        size_t idx = (size_t)row * N + col;
        float v = acc[i][j][ii] + bb;
        if constexpr (EPI == 0) {
          ((ushort*)Cv)[idx] = f2b(v);
        } else if constexpr (EPI == 1) {
          float gl = 0.5f * v * (1.0f + erff(v * 0.70710678118f));
          ((ushort*)Cv)[idx] = f2b(gl);
        } else {
          ((float*)Cv)[idx] = v + resid[idx];
        }
      }
    }
  }
}

// ---------------------------------------------------------------------------
// Attention: one block (256 thr = 4 waves) per (b, head).
// qkv bf16 [12800, 3072] (Q at col 0, K at 1024, V at 2048; head-major 64).
// scores = QK^T/8 + Q.pos[q-k+199]^T  (causal), softmax, ctx = P.V -> bf16.
// ---------------------------------------------------------------------------
__global__ __launch_bounds__(256) void attn_kernel(
    const ushort* __restrict__ qkv, const float* __restrict__ pos,
    ushort* __restrict__ ctx) {
  int bh = blockIdx.x;
  int b = bh >> 4, h = bh & 15;
  __shared__ __align__(16) ushort Ks[S_LEN][72];
  __shared__ __align__(16) ushort Vs[S_LEN][72];
  __shared__ float Ps[4][256];
  __shared__ float Qs[4][64];
  int t = threadIdx.x, lane = t & 63, wave = t >> 6;
  const size_t base = ((size_t)b * S_LEN) * 3072 + h * 64;

  // stage K and V (bf16) into LDS, 16B chunks
  for (int i = t; i < S_LEN * 8; i += 256) {
    int k = i >> 3, d0 = (i & 7) * 8;
    *(uint4*)&Ks[k][d0] = *(const uint4*)&qkv[base + (size_t)k * 3072 + 1024 + d0];
    *(uint4*)&Vs[k][d0] = *(const uint4*)&qkv[base + (size_t)k * 3072 + 2048 + d0];
  }
  __syncthreads();

  for (int q = wave; q < S_LEN; q += 4) {   // all 4 waves do exactly 50 iters
    size_t qoff = base + (size_t)q * 3072;
    __syncthreads();
    Qs[wave][lane] = b2f(qkv[qoff + lane]);
    __syncthreads();

    // scores: lane handles k = lane, lane+64, ...
    float sc[4];
    int nj = 0;
    float lmax = -3.0e38f;
    for (int k = lane; k <= q; k += 64) {
      float ak0 = 0, ak1 = 0, ap0 = 0, ap1 = 0;
      const float* pr = pos + (size_t)(q - k + 199) * 64;
      const float* qsw = &Qs[wave][0];
#pragma unroll
      for (int d0 = 0; d0 < 64; d0 += 8) {
        union { uint4 v; ushort u[8]; } kk;
        kk.v = *(const uint4*)&Ks[k][d0];
        float4 pa = *(const float4*)(pr + d0);
        float4 pb = *(const float4*)(pr + d0 + 4);
        ak0 += qsw[d0 + 0] * b2f(kk.u[0]); ap0 += qsw[d0 + 0] * pa.x;
        ak1 += qsw[d0 + 1] * b2f(kk.u[1]); ap1 += qsw[d0 + 1] * pa.y;
        ak0 += qsw[d0 + 2] * b2f(kk.u[2]); ap0 += qsw[d0 + 2] * pa.z;
        ak1 += qsw[d0 + 3] * b2f(kk.u[3]); ap1 += qsw[d0 + 3] * pa.w;
        ak0 += qsw[d0 + 4] * b2f(kk.u[4]); ap0 += qsw[d0 + 4] * pb.x;
        ak1 += qsw[d0 + 5] * b2f(kk.u[5]); ap1 += qsw[d0 + 5] * pb.y;
        ak0 += qsw[d0 + 6] * b2f(kk.u[6]); ap0 += qsw[d0 + 6] * pb.z;
        ak1 += qsw[d0 + 7] * b2f(kk.u[7]); ap1 += qsw[d0 + 7] * pb.w;
      }
      float s = (ak0 + ak1) * 0.125f + (ap0 + ap1);
      sc[nj++] = s;
      lmax = fmaxf(lmax, s);
    }
#pragma unroll
    for (int off = 32; off; off >>= 1) lmax = fmaxf(lmax, __shfl_xor(lmax, off));

    float lsum = 0.0f;
    {
      int j = 0;
      for (int k = lane; k <= q; k += 64, ++j) {
        float e = __expf(sc[j] - lmax);
        Ps[wave][k] = e;
        lsum += e;
      }
    }
#pragma unroll
    for (int off = 32; off; off >>= 1) lsum += __shfl_xor(lsum, off);
    float rsum = 1.0f / lsum;
    __syncthreads();

    // PV: lane = d
    float a0 = 0, a1 = 0, a2 = 0, a3 = 0;
    int k = 0;
    for (; k + 3 <= q; k += 4) {
      a0 += Ps[wave][k    ] * b2f(Vs[k    ][lane]);
      a1 += Ps[wave][k + 1] * b2f(Vs[k + 1][lane]);
      a2 += Ps[wave][k + 2] * b2f(Vs[k + 2][lane]);
      a3 += Ps[wave][k + 3] * b2f(Vs[k + 3][lane]);
    }
    for (; k <= q; ++k) a0 += Ps[wave][k] * b2f(Vs[k][lane]);
    float od = (a0 + a1 + a2 + a3) * rsum;
    ctx[((size_t)(b * S_LEN + q)) * H_DIM + h * 64 + lane] = f2b(od);
  }
}

// ---------------------------------------------------------------------------
// Launcher.  Workspace layout (aliased; peak ~124 MB):
//   [weights bf16^T: 25.2 MB][qkv 78.6 MB -> later h2(26.2)+gelu chunk(52.4)]
//   [hbf 26.2 MB -> later ctx]          res2 lives in d_out (fp32, 52.4 MB).
// ---------------------------------------------------------------------------
extern "C" void kernel_launch(void* const* d_in, const int* in_sizes, int n_in,
                              void* d_out, int out_size, void* d_ws, size_t ws_size,
                              hipStream_t stream) {
  (void)in_sizes; (void)n_in; (void)out_size; (void)ws_size;
  const float* x    = (const float*)d_in[0];
  const float* timev= (const float*)d_in[1];
  const float* wq   = (const float*)d_in[2];
  const float* bq   = (const float*)d_in[3];
  const float* wk   = (const float*)d_in[4];
  const float* bk   = (const float*)d_in[5];
  const float* wv   = (const float*)d_in[6];
  const float* bv   = (const float*)d_in[7];
  const float* wo   = (const float*)d_in[8];
  const float* bo   = (const float*)d_in[9];
  const float* wt   = (const float*)d_in[10];
  const float* bt   = (const float*)d_in[11];
  const float* pos  = (const float*)d_in[12];
  const float* g1   = (const float*)d_in[13];
  const float* be1  = (const float*)d_in[14];
  const float* g2   = (const float*)d_in[15];
  const float* be2  = (const float*)d_in[16];
  const float* w1   = (const float*)d_in[17];
  const float* bf1  = (const float*)d_in[18];
  const float* w2   = (const float*)d_in[19];
  const float* bf2  = (const float*)d_in[20];

  char* ws = (char*)d_ws;
  ushort* wqkv_t = (ushort*)ws;   ws += (size_t)3072 * 1024 * 2;   //  6.29 MB
  ushort* wo_t   = (ushort*)ws;   ws += (size_t)1024 * 1024 * 2;   //  2.10 MB
  ushort* w1_t   = (ushort*)ws;   ws += (size_t)4096 * 1024 * 2;   //  8.39 MB
  ushort* w2_t   = (ushort*)ws;   ws += (size_t)1024 * 4096 * 2;   //  8.39 MB
  float*  bqkv   = (float*)ws;    ws += (size_t)16384;             //  16 KB (3072 used)
  // region R1: qkv during attention; afterwards h2 + gelu chunk
  char* r1 = ws;                  ws += (size_t)NROWS * 3072 * 2;  // 78.64 MB
  ushort* qkv  = (ushort*)r1;
  ushort* h2   = (ushort*)r1;                                      // 26.21 MB
  ushort* gbuf = (ushort*)(r1 + (size_t)NROWS * H_DIM * 2);        // 52.43 MB (6400-row chunk)
  // region R2: hbf, then ctx
  char* r2 = ws;                  ws += (size_t)NROWS * 1024 * 2;  // 26.21 MB
  ushort* hbf = (ushort*)r2;
  ushort* ctx = (ushort*)r2;
  // res2 lives in d_out
  float* res2 = (float*)d_out;

  dim3 tb(32, 8);
  // weight transposes (fp32 -> bf16, [K,N] -> [N,K])
  transpose_to_bf16<<<dim3(32, 32), tb, 0, stream>>>(wq, wqkv_t,                 1024, 1024);
  transpose_to_bf16<<<dim3(32, 32), tb, 0, stream>>>(wk, wqkv_t + 1024 * 1024,   1024, 1024);
  transpose_to_bf16<<<dim3(32, 32), tb, 0, stream>>>(wv, wqkv_t + 2048 * 1024,   1024, 1024);
  transpose_to_bf16<<<dim3(32, 32), tb, 0, stream>>>(wo, wo_t,                   1024, 1024);
  transpose_to_bf16<<<dim3(128, 32), tb, 0, stream>>>(w1, w1_t,                  1024, 4096);
  transpose_to_bf16<<<dim3(32, 128), tb, 0, stream>>>(w2, w2_t,                  4096, 1024);
  concat_bias<<<12, 256, 0, stream>>>(bq, bk, bv, bqkv);

  // LN1 + time embed -> hbf (bf16)
  ln_kernel<1><<<NROWS, 256, 0, stream>>>(x, g1, be1, timev, wt, bt, hbf);

  // fused QKV GEMM: [12800,1024] x [3072,1024]^T -> qkv bf16
  gemm_bt<0><<<dim3(24, 100), 256, 0, stream>>>(hbf, wqkv_t, bqkv, qkv, nullptr,
                                                NROWS, 3072, 1024);
  // attention: qkv -> ctx (overwrites hbf region; hbf is dead now)
  attn_kernel<<<B_SZ * NHEAD, 256, 0, stream>>>(qkv, pos, ctx);

  // out = ctx @ wo + bo + x   (fp32, into d_out as res2)
  gemm_bt<2><<<dim3(8, 100), 256, 0, stream>>>(ctx, wo_t, bo, res2, x,
                                               NROWS, 1024, 1024);
  // LN2 -> h2 (bf16, overwrites qkv region; qkv is dead now)
  ln_kernel<0><<<NROWS, 256, 0, stream>>>(res2, g2, be2, nullptr, nullptr, nullptr, h2);

  // FF in 2 row-chunks of 6400 (gelu buffer fits in the freed qkv region)
  for (int c = 0; c < 2; ++c) {
    size_t ro = (size_t)c * 6400;
    // FF1 + exact GELU -> gbuf (bf16)
    gemm_bt<1><<<dim3(32, 50), 256, 0, stream>>>(h2 + ro * 1024, w1_t, bf1, gbuf, nullptr,
                                                 6400, 4096, 1024);
    // FF2 + res2 -> d_out (fp32, in place over res2 rows of this chunk)
    gemm_bt<2><<<dim3(8, 50), 256, 0, stream>>>(gbuf, w2_t, bf2, (float*)d_out + ro * 1024,
                                                res2 + ro * 1024, 6400, 1024, 4096);
  }
}

// Round 3
// 880.611 us; speedup vs baseline: 1.9165x; 1.9165x over previous
//
#include <hip/hip_runtime.h>

// Problem constants
#define B_SZ   64
#define S_LEN  200
#define H_DIM  1024
#define NHEAD  16
#define HDIM   64
#define FF_DIM 4096
#define NROWS  (B_SZ * S_LEN)   // 12800

typedef __bf16 bf16x8 __attribute__((ext_vector_type(8)));
typedef float  f32x4  __attribute__((ext_vector_type(4)));

__device__ __forceinline__ float b2f(ushort u) {
  return __uint_as_float(((unsigned int)u) << 16);
}
__device__ __forceinline__ ushort f2b(float f) {
  unsigned int u = __float_as_uint(f);
  u += 0x7fffu + ((u >> 16) & 1u);   // RNE
  return (ushort)(u >> 16);
}
__device__ __forceinline__ bf16x8 ld_g16(const ushort* p) {   // 16B global load
  union { uint4 u; bf16x8 v; } r; r.u = *(const uint4*)p; return r.v;
}
__device__ __forceinline__ bf16x8 ld_lds8x2(const ushort* p) { // 2x ds_read_b64
  union { uint2 u[2]; bf16x8 v; } r;
  r.u[0] = *(const uint2*)p;
  r.u[1] = *(const uint2*)(p + 4);
  return r.v;
}

// ---------------------------------------------------------------------------
// Transpose fp32 [K,N] -> bf16 [N,K]
// ---------------------------------------------------------------------------
__global__ __launch_bounds__(256) void transpose_to_bf16(
    const float* __restrict__ w, ushort* __restrict__ wt, int K, int N) {
  __shared__ float tile[32][33];
  int nb = blockIdx.x * 32, kb = blockIdx.y * 32;
  int tx = threadIdx.x, ty = threadIdx.y;  // 32 x 8
#pragma unroll
  for (int i = 0; i < 4; ++i) {
    int k = kb + ty + i * 8;
    tile[ty + i * 8][tx] = w[(size_t)k * N + nb + tx];
  }
  __syncthreads();
#pragma unroll
  for (int i = 0; i < 4; ++i) {
    int n = nb + ty + i * 8;
    wt[(size_t)n * K + kb + tx] = f2b(tile[tx][ty + i * 8]);
  }
}

// ---------------------------------------------------------------------------
// Concat 3 biases of 1024 into one 3072 vector
// ---------------------------------------------------------------------------
__global__ void concat_bias(const float* __restrict__ bq, const float* __restrict__ bk,
                            const float* __restrict__ bv, float* __restrict__ o) {
  int i = blockIdx.x * 256 + threadIdx.x;
  if (i < 1024) o[i] = bq[i];
  else if (i < 2048) o[i] = bk[i - 1024];
  else if (i < 3072) o[i] = bv[i - 2048];
}

// ---------------------------------------------------------------------------
// pos rows 199..398 (the causal-reachable range) -> bf16 [200][64]
// ---------------------------------------------------------------------------
__global__ void pos_to_bf16(const float* __restrict__ pos, ushort* __restrict__ pb) {
  int i = blockIdx.x * 256 + threadIdx.x;   // 50 blocks x 256 = 12800
  pb[i] = f2b(pos[(size_t)199 * 64 + i]);
}

// ---------------------------------------------------------------------------
// LayerNorm (fp32 in) -> bf16 out.  HAS_TIME: += time[r]*wt[c] + bt[c]
// ---------------------------------------------------------------------------
template <int HAS_TIME>
__global__ __launch_bounds__(256) void ln_kernel(
    const float* __restrict__ x, const float* __restrict__ g, const float* __restrict__ be,
    const float* __restrict__ tv, const float* __restrict__ wt, const float* __restrict__ bt,
    ushort* __restrict__ out) {
  int r = blockIdx.x, t = threadIdx.x;
  const float4* xr = (const float4*)(x + (size_t)r * H_DIM);
  float4 xv = xr[t];
  float s  = xv.x + xv.y + xv.z + xv.w;
  float s2 = xv.x * xv.x + xv.y * xv.y + xv.z * xv.z + xv.w * xv.w;
#pragma unroll
  for (int off = 32; off; off >>= 1) {
    s  += __shfl_xor(s, off);
    s2 += __shfl_xor(s2, off);
  }
  __shared__ float red[8];
  int lane = t & 63, wid = t >> 6;
  if (lane == 0) { red[wid] = s; red[4 + wid] = s2; }
  __syncthreads();
  float S  = red[0] + red[1] + red[2] + red[3];
  float S2 = red[4] + red[5] + red[6] + red[7];
  float m    = S * (1.0f / H_DIM);
  float var  = S2 * (1.0f / H_DIM) - m * m;
  float rstd = rsqrtf(var + 1e-5f);
  float tval = HAS_TIME ? tv[r] : 0.0f;
  float4 gv = ((const float4*)g)[t];
  float4 bv = ((const float4*)be)[t];
  float v0 = (xv.x - m) * rstd * gv.x + bv.x;
  float v1 = (xv.y - m) * rstd * gv.y + bv.y;
  float v2 = (xv.z - m) * rstd * gv.z + bv.z;
  float v3 = (xv.w - m) * rstd * gv.w + bv.w;
  if (HAS_TIME) {
    float4 wv = ((const float4*)wt)[t];
    float4 btv = ((const float4*)bt)[t];
    v0 += tval * wv.x + btv.x;
    v1 += tval * wv.y + btv.y;
    v2 += tval * wv.z + btv.z;
    v3 += tval * wv.w + btv.w;
  }
  ushort4 o;
  o.x = f2b(v0); o.y = f2b(v1); o.z = f2b(v2); o.w = f2b(v3);
  ((ushort4*)(out + (size_t)r * H_DIM))[t] = o;
}

// ---------------------------------------------------------------------------
// bf16 MFMA GEMM: C[M,N] = A[M,K] * Bt[N,K]^T + bias[N]  (+ epilogue)
// EPI 0: bf16 out.  EPI 1: exact GELU -> bf16.  EPI 2: +resid -> fp32 out.
// ---------------------------------------------------------------------------
template <int EPI>
__global__ __launch_bounds__(256) void gemm_bt(
    const ushort* __restrict__ A, const ushort* __restrict__ Bt,
    const float* __restrict__ bias, void* __restrict__ Cv,
    const float* __restrict__ resid, int M, int N, int K) {
  __shared__ __align__(16) ushort As[128][40];
  __shared__ __align__(16) ushort Bs[128][40];
  int t = threadIdx.x;
  int lane = t & 63, wave = t >> 6;
  int wm = wave >> 1, wn = wave & 1;
  int r15 = lane & 15, quad = lane >> 4;
  size_t row0 = (size_t)blockIdx.y * 128;
  size_t col0 = (size_t)blockIdx.x * 128;
  f32x4 acc[4][4] = {};

  for (int k0 = 0; k0 < K; k0 += 32) {
#pragma unroll
    for (int u = 0; u < 2; ++u) {
      int c = u * 256 + t;
      int row = c >> 2, cc = (c & 3) * 8;
      *(uint4*)&As[row][cc] = *(const uint4*)&A[(row0 + row) * K + k0 + cc];
      *(uint4*)&Bs[row][cc] = *(const uint4*)&Bt[(col0 + row) * K + k0 + cc];
    }
    __syncthreads();
    bf16x8 af[4], bfr[4];
#pragma unroll
    for (int i = 0; i < 4; ++i)
      af[i] = *(const bf16x8*)&As[wm * 64 + i * 16 + r15][quad * 8];
#pragma unroll
    for (int j = 0; j < 4; ++j)
      bfr[j] = *(const bf16x8*)&Bs[wn * 64 + j * 16 + r15][quad * 8];
#pragma unroll
    for (int i = 0; i < 4; ++i)
#pragma unroll
      for (int j = 0; j < 4; ++j)
        acc[i][j] = __builtin_amdgcn_mfma_f32_16x16x32_bf16(af[i], bfr[j], acc[i][j], 0, 0, 0);
    __syncthreads();
  }

  int mbase = (int)row0 + wm * 64;
  int nbase = (int)col0 + wn * 64;
#pragma unroll
  for (int i = 0; i < 4; ++i) {
#pragma unroll
    for (int j = 0; j < 4; ++j) {
      int col = nbase + j * 16 + r15;
      float bb = bias[col];
#pragma unroll
      for (int ii = 0; ii < 4; ++ii) {
        int row = mbase + i * 16 + quad * 4 + ii;
        size_t idx = (size_t)row * N + col;
        float v = acc[i][j][ii] + bb;
        if constexpr (EPI == 0) {
          ((ushort*)Cv)[idx] = f2b(v);
        } else if constexpr (EPI == 1) {
          float gl = 0.5f * v * (1.0f + erff(v * 0.70710678118f));
          ((ushort*)Cv)[idx] = f2b(gl);
        } else {
          ((float*)Cv)[idx] = v + resid[idx];
        }
      }
    }
  }
}

// ---------------------------------------------------------------------------
// MFMA attention.  One block (4 waves) per (b,h).
// scores = (Q@K^T)*0.125 + T[q, q-k],  T = Q@P^T  (P = pos_bf, rows d=q-k).
// Per-wave q-strips of 16 rows; S strip in registers; T/exp(S) share the
// per-wave LDS buffer Pw; V transposed once into Vt.  Causal tile skipping.
// ---------------------------------------------------------------------------
#define PW_STRIDE 228   // elems per row; 456B: 8B-aligned (b64 reads), ~4-way banks
__global__ __launch_bounds__(256) void attn_kernel(
    const ushort* __restrict__ qkv, const ushort* __restrict__ pos_bf,
    ushort* __restrict__ ctx) {
  int bh = blockIdx.x;
  int b = bh >> 4, h = bh & 15;
  __shared__ ushort Vt[64][PW_STRIDE];       // V^T: Vt[d][k]
  __shared__ ushort Pw[4][16][PW_STRIDE];    // per-wave: T strip, then exp(S)
  int t = threadIdx.x, lane = t & 63, wave = t >> 6;
  int r15 = lane & 15, quad = lane >> 4;
  const size_t base = ((size_t)b * S_LEN) * 3072 + (size_t)h * 64;

  // zero Vt pad cols 200..227
  for (int i = t; i < 64 * 28; i += 256) Vt[i / 28][200 + (i % 28)] = 0;
  // stage V transposed: read 2 rows x 8 cols, write 8 b32 (two ushorts each)
  for (int i = t; i < 800; i += 256) {
    int kp = i >> 3, d0 = (i & 7) * 8;
    int k = kp * 2;
    union { uint4 v; ushort u[8]; } r0, r1;
    r0.v = *(const uint4*)&qkv[base + (size_t)k * 3072 + 2048 + d0];
    r1.v = *(const uint4*)&qkv[base + (size_t)(k + 1) * 3072 + 2048 + d0];
#pragma unroll
    for (int j = 0; j < 8; ++j) {
      ushort2 w2; w2.x = r0.u[j]; w2.y = r1.u[j];
      *(ushort2*)&Vt[d0 + j][k] = w2;
    }
  }
  __syncthreads();

  for (int qt = wave; qt < 13; qt += 4) {
    int q0 = qt * 16;
    int qrow = q0 + r15; if (qrow > 199) qrow = 199;
    const ushort* qp = qkv + base + (size_t)qrow * 3072;
    bf16x8 aq0 = ld_g16(qp + quad * 8);
    bf16x8 aq1 = ld_g16(qp + 32 + quad * 8);
    ushort* pw = &Pw[wave][0][0];

    // ---- Phase 1: T strip = Q @ P^T, tiles dt = 0..qt -> Pw (bf16) ----
#pragma unroll
    for (int dt = 0; dt < 13; ++dt) {
      if (dt > qt) continue;
      int prow = dt * 16 + r15; if (prow > 199) prow = 199;
      const ushort* pp = pos_bf + (size_t)prow * 64;
      bf16x8 p0 = ld_g16(pp + quad * 8);
      bf16x8 p1 = ld_g16(pp + 32 + quad * 8);
      f32x4 tt = {};
      tt = __builtin_amdgcn_mfma_f32_16x16x32_bf16(aq0, p0, tt, 0, 0, 0);
      tt = __builtin_amdgcn_mfma_f32_16x16x32_bf16(aq1, p1, tt, 0, 0, 0);
#pragma unroll
      for (int ii = 0; ii < 4; ++ii)
        pw[(quad * 4 + ii) * PW_STRIDE + dt * 16 + r15] = f2b(tt[ii]);
    }

    // ---- Phase 2: scores S = QK^T*0.125 + gather(T), tiles kt = 0..qt ----
    f32x4 sreg[13];
    float rowmax[4] = {-3.0e38f, -3.0e38f, -3.0e38f, -3.0e38f};
#pragma unroll
    for (int kt = 0; kt < 13; ++kt) {
      if (kt > qt) continue;
      int krow = kt * 16 + r15; if (krow > 199) krow = 199;
      const ushort* kp = qkv + base + (size_t)krow * 3072 + 1024;
      bf16x8 k0 = ld_g16(kp + quad * 8);
      bf16x8 k1 = ld_g16(kp + 32 + quad * 8);
      f32x4 s = {};
      s = __builtin_amdgcn_mfma_f32_16x16x32_bf16(aq0, k0, s, 0, 0, 0);
      s = __builtin_amdgcn_mfma_f32_16x16x32_bf16(aq1, k1, s, 0, 0, 0);
      int k = kt * 16 + r15;
#pragma unroll
      for (int ii = 0; ii < 4; ++ii) {
        int q = q0 + quad * 4 + ii;
        float v;
        if (k <= q) {
          v = s[ii] * 0.125f + b2f(pw[(quad * 4 + ii) * PW_STRIDE + (q - k)]);
        } else {
          v = -1.0e30f;
        }
        s[ii] = v;
        rowmax[ii] = fmaxf(rowmax[ii], v);
      }
      sreg[kt] = s;
    }
#pragma unroll
    for (int off = 8; off; off >>= 1)
#pragma unroll
      for (int ii = 0; ii < 4; ++ii)
        rowmax[ii] = fmaxf(rowmax[ii], __shfl_xor(rowmax[ii], off));

    // exp + rowsum -> Pw (bf16), overwriting T
    float rsum[4] = {0.f, 0.f, 0.f, 0.f};
#pragma unroll
    for (int kt = 0; kt < 13; ++kt) {
      if (kt > qt) continue;
#pragma unroll
      for (int ii = 0; ii < 4; ++ii) {
        float e = __expf(sreg[kt][ii] - rowmax[ii]);
        rsum[ii] += e;
        pw[(quad * 4 + ii) * PW_STRIDE + kt * 16 + r15] = f2b(e);
      }
    }
    if ((qt & 1) == 0) {   // pad to a 32-multiple of k for the PV pass
#pragma unroll
      for (int ii = 0; ii < 4; ++ii)
        pw[(quad * 4 + ii) * PW_STRIDE + (qt + 1) * 16 + r15] = 0;
    }
#pragma unroll
    for (int off = 8; off; off >>= 1)
#pragma unroll
      for (int ii = 0; ii < 4; ++ii)
        rsum[ii] += __shfl_xor(rsum[ii], off);
    float rinv[4];
#pragma unroll
    for (int ii = 0; ii < 4; ++ii) rinv[ii] = 1.0f / rsum[ii];

    // ---- Phase 3: ctx = exp(S) @ V ----
    int nk = (q0 + 15) / 32 + 1;
    f32x4 acc[4] = {};
#pragma unroll
    for (int k32 = 0; k32 < 7; ++k32) {
      if (k32 >= nk) continue;
      bf16x8 ap = ld_lds8x2(&pw[r15 * PW_STRIDE + k32 * 32 + quad * 8]);
#pragma unroll
      for (int n = 0; n < 4; ++n) {
        bf16x8 bv = ld_lds8x2(&Vt[n * 16 + r15][k32 * 32 + quad * 8]);
        acc[n] = __builtin_amdgcn_mfma_f32_16x16x32_bf16(ap, bv, acc[n], 0, 0, 0);
      }
    }
#pragma unroll
    for (int n = 0; n < 4; ++n)
#pragma unroll
      for (int ii = 0; ii < 4; ++ii) {
        int q = q0 + quad * 4 + ii;
        if (q < S_LEN)
          ctx[((size_t)(b * S_LEN + q)) * H_DIM + h * 64 + n * 16 + r15] =
              f2b(acc[n][ii] * rinv[ii]);
      }
  }
}

// ---------------------------------------------------------------------------
// Launcher.  Workspace layout (aliased; peak ~124 MB):
//   [weights bf16^T: 25.2 MB][pos_bf 25.6KB][qkv 78.6 MB -> h2+gelu chunk]
//   [hbf 26.2 MB -> ctx]          res2 lives in d_out (fp32, 52.4 MB).
// ---------------------------------------------------------------------------
extern "C" void kernel_launch(void* const* d_in, const int* in_sizes, int n_in,
                              void* d_out, int out_size, void* d_ws, size_t ws_size,
                              hipStream_t stream) {
  (void)in_sizes; (void)n_in; (void)out_size; (void)ws_size;
  const float* x    = (const float*)d_in[0];
  const float* timev= (const float*)d_in[1];
  const float* wq   = (const float*)d_in[2];
  const float* bq   = (const float*)d_in[3];
  const float* wk   = (const float*)d_in[4];
  const float* bk   = (const float*)d_in[5];
  const float* wv   = (const float*)d_in[6];
  const float* bv   = (const float*)d_in[7];
  const float* wo   = (const float*)d_in[8];
  const float* bo   = (const float*)d_in[9];
  const float* wt   = (const float*)d_in[10];
  const float* bt   = (const float*)d_in[11];
  const float* pos  = (const float*)d_in[12];
  const float* g1   = (const float*)d_in[13];
  const float* be1  = (const float*)d_in[14];
  const float* g2   = (const float*)d_in[15];
  const float* be2  = (const float*)d_in[16];
  const float* w1   = (const float*)d_in[17];
  const float* bf1  = (const float*)d_in[18];
  const float* w2   = (const float*)d_in[19];
  const float* bf2  = (const float*)d_in[20];

  char* ws = (char*)d_ws;
  ushort* wqkv_t = (ushort*)ws;   ws += (size_t)3072 * 1024 * 2;   //  6.29 MB
  ushort* wo_t   = (ushort*)ws;   ws += (size_t)1024 * 1024 * 2;   //  2.10 MB
  ushort* w1_t   = (ushort*)ws;   ws += (size_t)4096 * 1024 * 2;   //  8.39 MB
  ushort* w2_t   = (ushort*)ws;   ws += (size_t)1024 * 4096 * 2;   //  8.39 MB
  float*  bqkv   = (float*)ws;    ws += (size_t)16384;             //  16 KB
  ushort* pos_bf = (ushort*)ws;   ws += (size_t)200 * 64 * 2;      //  25.6 KB
  // region R1: qkv during attention; afterwards h2 + gelu chunk
  char* r1 = ws;                  ws += (size_t)NROWS * 3072 * 2;  // 78.64 MB
  ushort* qkv  = (ushort*)r1;
  ushort* h2   = (ushort*)r1;                                      // 26.21 MB
  ushort* gbuf = (ushort*)(r1 + (size_t)NROWS * H_DIM * 2);        // 52.43 MB
  // region R2: hbf, then ctx
  char* r2 = ws;                  ws += (size_t)NROWS * 1024 * 2;  // 26.21 MB
  ushort* hbf = (ushort*)r2;
  ushort* ctx = (ushort*)r2;
  float* res2 = (float*)d_out;

  dim3 tb(32, 8);
  transpose_to_bf16<<<dim3(32, 32), tb, 0, stream>>>(wq, wqkv_t,                 1024, 1024);
  transpose_to_bf16<<<dim3(32, 32), tb, 0, stream>>>(wk, wqkv_t + 1024 * 1024,   1024, 1024);
  transpose_to_bf16<<<dim3(32, 32), tb, 0, stream>>>(wv, wqkv_t + 2048 * 1024,   1024, 1024);
  transpose_to_bf16<<<dim3(32, 32), tb, 0, stream>>>(wo, wo_t,                   1024, 1024);
  transpose_to_bf16<<<dim3(128, 32), tb, 0, stream>>>(w1, w1_t,                  1024, 4096);
  transpose_to_bf16<<<dim3(32, 128), tb, 0, stream>>>(w2, w2_t,                  4096, 1024);
  concat_bias<<<12, 256, 0, stream>>>(bq, bk, bv, bqkv);
  pos_to_bf16<<<50, 256, 0, stream>>>(pos, pos_bf);

  // LN1 + time embed -> hbf (bf16)
  ln_kernel<1><<<NROWS, 256, 0, stream>>>(x, g1, be1, timev, wt, bt, hbf);

  // fused QKV GEMM: [12800,1024] x [3072,1024]^T -> qkv bf16
  gemm_bt<0><<<dim3(24, 100), 256, 0, stream>>>(hbf, wqkv_t, bqkv, qkv, nullptr,
                                                NROWS, 3072, 1024);
  // MFMA attention: qkv -> ctx (overwrites hbf region; hbf is dead now)
  attn_kernel<<<B_SZ * NHEAD, 256, 0, stream>>>(qkv, pos_bf, ctx);

  // out = ctx @ wo + bo + x   (fp32, into d_out as res2)
  gemm_bt<2><<<dim3(8, 100), 256, 0, stream>>>(ctx, wo_t, bo, res2, x,
                                               NROWS, 1024, 1024);
  // LN2 -> h2 (bf16, overwrites qkv region; qkv is dead now)
  ln_kernel<0><<<NROWS, 256, 0, stream>>>(res2, g2, be2, nullptr, nullptr, nullptr, h2);

  // FF in 2 row-chunks of 6400 (gelu buffer fits in the freed qkv region)
  for (int c = 0; c < 2; ++c) {
    size_t ro = (size_t)c * 6400;
    gemm_bt<1><<<dim3(32, 50), 256, 0, stream>>>(h2 + ro * 1024, w1_t, bf1, gbuf, nullptr,
                                                 6400, 4096, 1024);
    gemm_bt<2><<<dim3(8, 50), 256, 0, stream>>>(gbuf, w2_t, bf2, (float*)d_out + ro * 1024,
                                                res2 + ro * 1024, 6400, 1024, 4096);
  }
}

// Round 4
// 856.156 us; speedup vs baseline: 1.9713x; 1.0286x over previous
//
#include <hip/hip_runtime.h>

// Problem constants
#define B_SZ   64
#define S_LEN  200
#define H_DIM  1024
#define NHEAD  16
#define HDIM   64
#define FF_DIM 4096
#define NROWS  (B_SZ * S_LEN)   // 12800

typedef __bf16 bf16x8 __attribute__((ext_vector_type(8)));
typedef float  f32x4  __attribute__((ext_vector_type(4)));

#define GLOBAL_AS __attribute__((address_space(1)))
#define LDS_AS    __attribute__((address_space(3)))

__device__ __forceinline__ void g2lds16(const void* g, void* l) {
  __builtin_amdgcn_global_load_lds((const GLOBAL_AS void*)g, (LDS_AS void*)l, 16, 0, 0);
}

__device__ __forceinline__ float b2f(ushort u) {
  return __uint_as_float(((unsigned int)u) << 16);
}
__device__ __forceinline__ ushort f2b(float f) {
  unsigned int u = __float_as_uint(f);
  u += 0x7fffu + ((u >> 16) & 1u);   // RNE
  return (ushort)(u >> 16);
}
__device__ __forceinline__ bf16x8 ld_g16(const ushort* p) {   // 16B global load
  union { uint4 u; bf16x8 v; } r; r.u = *(const uint4*)p; return r.v;
}
__device__ __forceinline__ bf16x8 ld_lds8x2(const ushort* p) { // 2x ds_read_b64
  union { uint2 u[2]; bf16x8 v; } r;
  r.u[0] = *(const uint2*)p;
  r.u[1] = *(const uint2*)(p + 4);
  return r.v;
}

// ---------------------------------------------------------------------------
// Transpose fp32 [K,N] -> bf16 [N,K]
// ---------------------------------------------------------------------------
__global__ __launch_bounds__(256) void transpose_to_bf16(
    const float* __restrict__ w, ushort* __restrict__ wt, int K, int N) {
  __shared__ float tile[32][33];
  int nb = blockIdx.x * 32, kb = blockIdx.y * 32;
  int tx = threadIdx.x, ty = threadIdx.y;  // 32 x 8
#pragma unroll
  for (int i = 0; i < 4; ++i) {
    int k = kb + ty + i * 8;
    tile[ty + i * 8][tx] = w[(size_t)k * N + nb + tx];
  }
  __syncthreads();
#pragma unroll
  for (int i = 0; i < 4; ++i) {
    int n = nb + ty + i * 8;
    wt[(size_t)n * K + kb + tx] = f2b(tile[tx][ty + i * 8]);
  }
}

// ---------------------------------------------------------------------------
// Concat 3 biases of 1024 into one 3072 vector
// ---------------------------------------------------------------------------
__global__ void concat_bias(const float* __restrict__ bq, const float* __restrict__ bk,
                            const float* __restrict__ bv, float* __restrict__ o) {
  int i = blockIdx.x * 256 + threadIdx.x;
  if (i < 1024) o[i] = bq[i];
  else if (i < 2048) o[i] = bk[i - 1024];
  else if (i < 3072) o[i] = bv[i - 2048];
}

// ---------------------------------------------------------------------------
// pos rows 199..398 (the causal-reachable range) -> bf16 [200][64]
// ---------------------------------------------------------------------------
__global__ void pos_to_bf16(const float* __restrict__ pos, ushort* __restrict__ pb) {
  int i = blockIdx.x * 256 + threadIdx.x;   // 50 blocks x 256 = 12800
  pb[i] = f2b(pos[(size_t)199 * 64 + i]);
}

// ---------------------------------------------------------------------------
// LayerNorm (fp32 in) -> bf16 out.  HAS_TIME: += time[r]*wt[c] + bt[c]
// ---------------------------------------------------------------------------
template <int HAS_TIME>
__global__ __launch_bounds__(256) void ln_kernel(
    const float* __restrict__ x, const float* __restrict__ g, const float* __restrict__ be,
    const float* __restrict__ tv, const float* __restrict__ wt, const float* __restrict__ bt,
    ushort* __restrict__ out) {
  int r = blockIdx.x, t = threadIdx.x;
  const float4* xr = (const float4*)(x + (size_t)r * H_DIM);
  float4 xv = xr[t];
  float s  = xv.x + xv.y + xv.z + xv.w;
  float s2 = xv.x * xv.x + xv.y * xv.y + xv.z * xv.z + xv.w * xv.w;
#pragma unroll
  for (int off = 32; off; off >>= 1) {
    s  += __shfl_xor(s, off);
    s2 += __shfl_xor(s2, off);
  }
  __shared__ float red[8];
  int lane = t & 63, wid = t >> 6;
  if (lane == 0) { red[wid] = s; red[4 + wid] = s2; }
  __syncthreads();
  float S  = red[0] + red[1] + red[2] + red[3];
  float S2 = red[4] + red[5] + red[6] + red[7];
  float m    = S * (1.0f / H_DIM);
  float var  = S2 * (1.0f / H_DIM) - m * m;
  float rstd = rsqrtf(var + 1e-5f);
  float tval = HAS_TIME ? tv[r] : 0.0f;
  float4 gv = ((const float4*)g)[t];
  float4 bv = ((const float4*)be)[t];
  float v0 = (xv.x - m) * rstd * gv.x + bv.x;
  float v1 = (xv.y - m) * rstd * gv.y + bv.y;
  float v2 = (xv.z - m) * rstd * gv.z + bv.z;
  float v3 = (xv.w - m) * rstd * gv.w + bv.w;
  if (HAS_TIME) {
    float4 wv = ((const float4*)wt)[t];
    float4 btv = ((const float4*)bt)[t];
    v0 += tval * wv.x + btv.x;
    v1 += tval * wv.y + btv.y;
    v2 += tval * wv.z + btv.z;
    v3 += tval * wv.w + btv.w;
  }
  ushort4 o;
  o.x = f2b(v0); o.y = f2b(v1); o.z = f2b(v2); o.w = f2b(v3);
  ((ushort4*)(out + (size_t)r * H_DIM))[t] = o;
}

// ---------------------------------------------------------------------------
// bf16 MFMA GEMM, m97-style: C[M,N] = A[M,K] * Bt[N,K]^T + bias[N] (+epilogue)
// EPI 0: bf16 out.  EPI 1: exact GELU -> bf16.  EPI 2: +resid -> fp32 out
//   (safe when Cv == resid: per-thread read-then-write of same idx).
// 128x128 tile, BK=32, 256 thr (4 waves 2x2), unpadded K-major LDS tiles
// staged via global_load_lds width=16 (direct HBM->LDS DMA, no VGPR trip).
// ---------------------------------------------------------------------------
template <int EPI>
__global__ __launch_bounds__(256) void gemm_bt(
    const ushort* __restrict__ A, const ushort* __restrict__ Bt,
    const float* __restrict__ bias, void* __restrict__ Cv,
    const float* __restrict__ resid, int M, int N, int K) {
  __shared__ __align__(16) ushort As[128 * 32];
  __shared__ __align__(16) ushort Bs[128 * 32];
  int t = threadIdx.x;
  int lane = t & 63, wave = t >> 6;
  int wm = wave >> 1, wn = wave & 1;
  int r15 = lane & 15, quad = lane >> 4;
  size_t row0 = (size_t)blockIdx.y * 128;
  size_t col0 = (size_t)blockIdx.x * 128;

  // staging: wave w covers rows w*32 .. w*32+31 of each tile, 2 DMA calls each.
  // lane l -> row (l>>2), in-row 16B chunk (l&3). LDS dest = base + lane*16.
  int srow = (lane >> 2), scol = (lane & 3) * 8;
  const ushort* ga0 = A  + (row0 + wave * 32 +      srow) * K + scol;
  const ushort* ga1 = A  + (row0 + wave * 32 + 16 + srow) * K + scol;
  const ushort* gb0 = Bt + (col0 + wave * 32 +      srow) * K + scol;
  const ushort* gb1 = Bt + (col0 + wave * 32 + 16 + srow) * K + scol;
  ushort* la0 = As + (wave * 32) * 32;
  ushort* la1 = As + (wave * 32 + 16) * 32;
  ushort* lb0 = Bs + (wave * 32) * 32;
  ushort* lb1 = Bs + (wave * 32 + 16) * 32;

  f32x4 acc[4][4] = {};

  for (int k0 = 0; k0 < K; k0 += 32) {
    g2lds16(ga0 + k0, la0);
    g2lds16(ga1 + k0, la1);
    g2lds16(gb0 + k0, lb0);
    g2lds16(gb1 + k0, lb1);
    __syncthreads();
    bf16x8 af[4], bfr[4];
#pragma unroll
    for (int i = 0; i < 4; ++i)
      af[i] = *(const bf16x8*)&As[(wm * 64 + i * 16 + r15) * 32 + quad * 8];
#pragma unroll
    for (int j = 0; j < 4; ++j)
      bfr[j] = *(const bf16x8*)&Bs[(wn * 64 + j * 16 + r15) * 32 + quad * 8];
#pragma unroll
    for (int i = 0; i < 4; ++i)
#pragma unroll
      for (int j = 0; j < 4; ++j)
        acc[i][j] = __builtin_amdgcn_mfma_f32_16x16x32_bf16(af[i], bfr[j], acc[i][j], 0, 0, 0);
    __syncthreads();
  }

  int mbase = (int)row0 + wm * 64;
  int nbase = (int)col0 + wn * 64;
#pragma unroll
  for (int i = 0; i < 4; ++i) {
#pragma unroll
    for (int j = 0; j < 4; ++j) {
      int col = nbase + j * 16 + r15;
      float bb = bias[col];
#pragma unroll
      for (int ii = 0; ii < 4; ++ii) {
        int row = mbase + i * 16 + quad * 4 + ii;
        size_t idx = (size_t)row * N + col;
        float v = acc[i][j][ii] + bb;
        if constexpr (EPI == 0) {
          ((ushort*)Cv)[idx] = f2b(v);
        } else if constexpr (EPI == 1) {
          float gl = 0.5f * v * (1.0f + erff(v * 0.70710678118f));
          ((ushort*)Cv)[idx] = f2b(gl);
        } else {
          ((float*)Cv)[idx] = v + resid[idx];
        }
      }
    }
  }
}

// ---------------------------------------------------------------------------
// MFMA attention.  One block (4 waves) per (b,h).
// scores = (Q@K^T)*0.125 + T[q, q-k],  T = Q@P^T  (P = pos_bf, rows d=q-k).
// ---------------------------------------------------------------------------
#define PW_STRIDE 228   // elems per row; 456B: 8B-aligned (b64 reads), ~4-way banks
__global__ __launch_bounds__(256) void attn_kernel(
    const ushort* __restrict__ qkv, const ushort* __restrict__ pos_bf,
    ushort* __restrict__ ctx) {
  int bh = blockIdx.x;
  int b = bh >> 4, h = bh & 15;
  __shared__ ushort Vt[64][PW_STRIDE];       // V^T: Vt[d][k]
  __shared__ ushort Pw[4][16][PW_STRIDE];    // per-wave: T strip, then exp(S)
  int t = threadIdx.x, lane = t & 63, wave = t >> 6;
  int r15 = lane & 15, quad = lane >> 4;
  const size_t base = ((size_t)b * S_LEN) * 3072 + (size_t)h * 64;

  // zero Vt pad cols 200..227
  for (int i = t; i < 64 * 28; i += 256) Vt[i / 28][200 + (i % 28)] = 0;
  // stage V transposed
  for (int i = t; i < 800; i += 256) {
    int kp = i >> 3, d0 = (i & 7) * 8;
    int k = kp * 2;
    union { uint4 v; ushort u[8]; } r0, r1;
    r0.v = *(const uint4*)&qkv[base + (size_t)k * 3072 + 2048 + d0];
    r1.v = *(const uint4*)&qkv[base + (size_t)(k + 1) * 3072 + 2048 + d0];
#pragma unroll
    for (int j = 0; j < 8; ++j) {
      ushort2 w2; w2.x = r0.u[j]; w2.y = r1.u[j];
      *(ushort2*)&Vt[d0 + j][k] = w2;
    }
  }
  __syncthreads();

  for (int qt = wave; qt < 13; qt += 4) {
    int q0 = qt * 16;
    int qrow = q0 + r15; if (qrow > 199) qrow = 199;
    const ushort* qp = qkv + base + (size_t)qrow * 3072;
    bf16x8 aq0 = ld_g16(qp + quad * 8);
    bf16x8 aq1 = ld_g16(qp + 32 + quad * 8);
    ushort* pw = &Pw[wave][0][0];

    // ---- Phase 1: T strip = Q @ P^T ----
#pragma unroll
    for (int dt = 0; dt < 13; ++dt) {
      if (dt > qt) continue;
      int prow = dt * 16 + r15; if (prow > 199) prow = 199;
      const ushort* pp = pos_bf + (size_t)prow * 64;
      bf16x8 p0 = ld_g16(pp + quad * 8);
      bf16x8 p1 = ld_g16(pp + 32 + quad * 8);
      f32x4 tt = {};
      tt = __builtin_amdgcn_mfma_f32_16x16x32_bf16(aq0, p0, tt, 0, 0, 0);
      tt = __builtin_amdgcn_mfma_f32_16x16x32_bf16(aq1, p1, tt, 0, 0, 0);
#pragma unroll
      for (int ii = 0; ii < 4; ++ii)
        pw[(quad * 4 + ii) * PW_STRIDE + dt * 16 + r15] = f2b(tt[ii]);
    }

    // ---- Phase 2: scores ----
    f32x4 sreg[13];
    float rowmax[4] = {-3.0e38f, -3.0e38f, -3.0e38f, -3.0e38f};
#pragma unroll
    for (int kt = 0; kt < 13; ++kt) {
      if (kt > qt) continue;
      int krow = kt * 16 + r15; if (krow > 199) krow = 199;
      const ushort* kp = qkv + base + (size_t)krow * 3072 + 1024;
      bf16x8 k0 = ld_g16(kp + quad * 8);
      bf16x8 k1 = ld_g16(kp + 32 + quad * 8);
      f32x4 s = {};
      s = __builtin_amdgcn_mfma_f32_16x16x32_bf16(aq0, k0, s, 0, 0, 0);
      s = __builtin_amdgcn_mfma_f32_16x16x32_bf16(aq1, k1, s, 0, 0, 0);
      int k = kt * 16 + r15;
#pragma unroll
      for (int ii = 0; ii < 4; ++ii) {
        int q = q0 + quad * 4 + ii;
        float v;
        if (k <= q) {
          v = s[ii] * 0.125f + b2f(pw[(quad * 4 + ii) * PW_STRIDE + (q - k)]);
        } else {
          v = -1.0e30f;
        }
        s[ii] = v;
        rowmax[ii] = fmaxf(rowmax[ii], v);
      }
      sreg[kt] = s;
    }
#pragma unroll
    for (int off = 8; off; off >>= 1)
#pragma unroll
      for (int ii = 0; ii < 4; ++ii)
        rowmax[ii] = fmaxf(rowmax[ii], __shfl_xor(rowmax[ii], off));

    float rsum[4] = {0.f, 0.f, 0.f, 0.f};
#pragma unroll
    for (int kt = 0; kt < 13; ++kt) {
      if (kt > qt) continue;
#pragma unroll
      for (int ii = 0; ii < 4; ++ii) {
        float e = __expf(sreg[kt][ii] - rowmax[ii]);
        rsum[ii] += e;
        pw[(quad * 4 + ii) * PW_STRIDE + kt * 16 + r15] = f2b(e);
      }
    }
    if ((qt & 1) == 0) {
#pragma unroll
      for (int ii = 0; ii < 4; ++ii)
        pw[(quad * 4 + ii) * PW_STRIDE + (qt + 1) * 16 + r15] = 0;
    }
#pragma unroll
    for (int off = 8; off; off >>= 1)
#pragma unroll
      for (int ii = 0; ii < 4; ++ii)
        rsum[ii] += __shfl_xor(rsum[ii], off);
    float rinv[4];
#pragma unroll
    for (int ii = 0; ii < 4; ++ii) rinv[ii] = 1.0f / rsum[ii];

    // ---- Phase 3: ctx = exp(S) @ V ----
    int nk = (q0 + 15) / 32 + 1;
    f32x4 acc[4] = {};
#pragma unroll
    for (int k32 = 0; k32 < 7; ++k32) {
      if (k32 >= nk) continue;
      bf16x8 ap = ld_lds8x2(&pw[r15 * PW_STRIDE + k32 * 32 + quad * 8]);
#pragma unroll
      for (int n = 0; n < 4; ++n) {
        bf16x8 bv = ld_lds8x2(&Vt[n * 16 + r15][k32 * 32 + quad * 8]);
        acc[n] = __builtin_amdgcn_mfma_f32_16x16x32_bf16(ap, bv, acc[n], 0, 0, 0);
      }
    }
#pragma unroll
    for (int n = 0; n < 4; ++n)
#pragma unroll
      for (int ii = 0; ii < 4; ++ii) {
        int q = q0 + quad * 4 + ii;
        if (q < S_LEN)
          ctx[((size_t)(b * S_LEN + q)) * H_DIM + h * 64 + n * 16 + r15] =
              f2b(acc[n][ii] * rinv[ii]);
      }
  }
}

// ---------------------------------------------------------------------------
// Launcher.  Workspace layout (aliased; peak ~124 MB):
//   [weights bf16^T: 25.2 MB][pos_bf 25.6KB][qkv 78.6 MB -> h2+gelu chunk]
//   [hbf 26.2 MB -> ctx]          res2 lives in d_out (fp32, 52.4 MB).
// ---------------------------------------------------------------------------
extern "C" void kernel_launch(void* const* d_in, const int* in_sizes, int n_in,
                              void* d_out, int out_size, void* d_ws, size_t ws_size,
                              hipStream_t stream) {
  (void)in_sizes; (void)n_in; (void)out_size; (void)ws_size;
  const float* x    = (const float*)d_in[0];
  const float* timev= (const float*)d_in[1];
  const float* wq   = (const float*)d_in[2];
  const float* bq   = (const float*)d_in[3];
  const float* wk   = (const float*)d_in[4];
  const float* bk   = (const float*)d_in[5];
  const float* wv   = (const float*)d_in[6];
  const float* bv   = (const float*)d_in[7];
  const float* wo   = (const float*)d_in[8];
  const float* bo   = (const float*)d_in[9];
  const float* wt   = (const float*)d_in[10];
  const float* bt   = (const float*)d_in[11];
  const float* pos  = (const float*)d_in[12];
  const float* g1   = (const float*)d_in[13];
  const float* be1  = (const float*)d_in[14];
  const float* g2   = (const float*)d_in[15];
  const float* be2  = (const float*)d_in[16];
  const float* w1   = (const float*)d_in[17];
  const float* bf1  = (const float*)d_in[18];
  const float* w2   = (const float*)d_in[19];
  const float* bf2  = (const float*)d_in[20];

  char* ws = (char*)d_ws;
  ushort* wqkv_t = (ushort*)ws;   ws += (size_t)3072 * 1024 * 2;   //  6.29 MB
  ushort* wo_t   = (ushort*)ws;   ws += (size_t)1024 * 1024 * 2;   //  2.10 MB
  ushort* w1_t   = (ushort*)ws;   ws += (size_t)4096 * 1024 * 2;   //  8.39 MB
  ushort* w2_t   = (ushort*)ws;   ws += (size_t)1024 * 4096 * 2;   //  8.39 MB
  float*  bqkv   = (float*)ws;    ws += (size_t)16384;             //  16 KB
  ushort* pos_bf = (ushort*)ws;   ws += (size_t)200 * 64 * 2;      //  25.6 KB
  // region R1: qkv during attention; afterwards h2 + gelu chunk
  char* r1 = ws;                  ws += (size_t)NROWS * 3072 * 2;  // 78.64 MB
  ushort* qkv  = (ushort*)r1;
  ushort* h2   = (ushort*)r1;                                      // 26.21 MB
  ushort* gbuf = (ushort*)(r1 + (size_t)NROWS * H_DIM * 2);        // 52.43 MB
  // region R2: hbf, then ctx
  char* r2 = ws;                  ws += (size_t)NROWS * 1024 * 2;  // 26.21 MB
  ushort* hbf = (ushort*)r2;
  ushort* ctx = (ushort*)r2;
  float* res2 = (float*)d_out;

  dim3 tb(32, 8);
  transpose_to_bf16<<<dim3(32, 32), tb, 0, stream>>>(wq, wqkv_t,                 1024, 1024);
  transpose_to_bf16<<<dim3(32, 32), tb, 0, stream>>>(wk, wqkv_t + 1024 * 1024,   1024, 1024);
  transpose_to_bf16<<<dim3(32, 32), tb, 0, stream>>>(wv, wqkv_t + 2048 * 1024,   1024, 1024);
  transpose_to_bf16<<<dim3(32, 32), tb, 0, stream>>>(wo, wo_t,                   1024, 1024);
  transpose_to_bf16<<<dim3(128, 32), tb, 0, stream>>>(w1, w1_t,                  1024, 4096);
  transpose_to_bf16<<<dim3(32, 128), tb, 0, stream>>>(w2, w2_t,                  4096, 1024);
  concat_bias<<<12, 256, 0, stream>>>(bq, bk, bv, bqkv);
  pos_to_bf16<<<50, 256, 0, stream>>>(pos, pos_bf);

  // LN1 + time embed -> hbf (bf16)
  ln_kernel<1><<<NROWS, 256, 0, stream>>>(x, g1, be1, timev, wt, bt, hbf);

  // fused QKV GEMM: [12800,1024] x [3072,1024]^T -> qkv bf16
  gemm_bt<0><<<dim3(24, 100), 256, 0, stream>>>(hbf, wqkv_t, bqkv, qkv, nullptr,
                                                NROWS, 3072, 1024);
  // MFMA attention: qkv -> ctx (overwrites hbf region; hbf is dead now)
  attn_kernel<<<B_SZ * NHEAD, 256, 0, stream>>>(qkv, pos_bf, ctx);

  // out = ctx @ wo + bo + x   (fp32, into d_out as res2)
  gemm_bt<2><<<dim3(8, 100), 256, 0, stream>>>(ctx, wo_t, bo, res2, x,
                                               NROWS, 1024, 1024);
  // LN2 -> h2 (bf16, overwrites qkv region; qkv is dead now)
  ln_kernel<0><<<NROWS, 256, 0, stream>>>(res2, g2, be2, nullptr, nullptr, nullptr, h2);

  // FF in 2 row-chunks of 6400 (gelu buffer fits in the freed qkv region)
  for (int c = 0; c < 2; ++c) {
    size_t ro = (size_t)c * 6400;
    gemm_bt<1><<<dim3(32, 50), 256, 0, stream>>>(h2 + ro * 1024, w1_t, bf1, gbuf, nullptr,
                                                 6400, 4096, 1024);
    gemm_bt<2><<<dim3(8, 50), 256, 0, stream>>>(gbuf, w2_t, bf2, (float*)d_out + ro * 1024,
                                                res2 + ro * 1024, 6400, 1024, 4096);
  }
}

// Round 5
// 806.777 us; speedup vs baseline: 2.0919x; 1.0612x over previous
//
#include <hip/hip_runtime.h>

// Problem constants
#define B_SZ   64
#define S_LEN  200
#define H_DIM  1024
#define NHEAD  16
#define HDIM   64
#define FF_DIM 4096
#define NROWS  (B_SZ * S_LEN)   // 12800

typedef __bf16 bf16x8 __attribute__((ext_vector_type(8)));
typedef float  f32x4  __attribute__((ext_vector_type(4)));

#define GLOBAL_AS __attribute__((address_space(1)))
#define LDS_AS    __attribute__((address_space(3)))

__device__ __forceinline__ void g2lds16(const void* g, void* l) {
  __builtin_amdgcn_global_load_lds((const GLOBAL_AS void*)g, (LDS_AS void*)l, 16, 0, 0);
}

__device__ __forceinline__ float b2f(ushort u) {
  return __uint_as_float(((unsigned int)u) << 16);
}
__device__ __forceinline__ ushort f2b(float f) {
  unsigned int u = __float_as_uint(f);
  u += 0x7fffu + ((u >> 16) & 1u);   // RNE
  return (ushort)(u >> 16);
}
__device__ __forceinline__ bf16x8 ld_g16(const ushort* p) {   // 16B global load
  union { uint4 u; bf16x8 v; } r; r.u = *(const uint4*)p; return r.v;
}
__device__ __forceinline__ bf16x8 ld_lds8x2(const ushort* p) { // 2x ds_read_b64
  union { uint2 u[2]; bf16x8 v; } r;
  r.u[0] = *(const uint2*)p;
  r.u[1] = *(const uint2*)(p + 4);
  return r.v;
}

// ---------------------------------------------------------------------------
// Transpose fp32 [K,N] -> bf16 [N,K]
// ---------------------------------------------------------------------------
__global__ __launch_bounds__(256) void transpose_to_bf16(
    const float* __restrict__ w, ushort* __restrict__ wt, int K, int N) {
  __shared__ float tile[32][33];
  int nb = blockIdx.x * 32, kb = blockIdx.y * 32;
  int tx = threadIdx.x, ty = threadIdx.y;  // 32 x 8
#pragma unroll
  for (int i = 0; i < 4; ++i) {
    int k = kb + ty + i * 8;
    tile[ty + i * 8][tx] = w[(size_t)k * N + nb + tx];
  }
  __syncthreads();
#pragma unroll
  for (int i = 0; i < 4; ++i) {
    int n = nb + ty + i * 8;
    wt[(size_t)n * K + kb + tx] = f2b(tile[tx][ty + i * 8]);
  }
}

// ---------------------------------------------------------------------------
// Concat 3 biases of 1024 into one 3072 vector
// ---------------------------------------------------------------------------
__global__ void concat_bias(const float* __restrict__ bq, const float* __restrict__ bk,
                            const float* __restrict__ bv, float* __restrict__ o) {
  int i = blockIdx.x * 256 + threadIdx.x;
  if (i < 1024) o[i] = bq[i];
  else if (i < 2048) o[i] = bk[i - 1024];
  else if (i < 3072) o[i] = bv[i - 2048];
}

// ---------------------------------------------------------------------------
// pos rows 199..398 (the causal-reachable range) -> bf16 [200][64]
// ---------------------------------------------------------------------------
__global__ void pos_to_bf16(const float* __restrict__ pos, ushort* __restrict__ pb) {
  int i = blockIdx.x * 256 + threadIdx.x;   // 50 blocks x 256 = 12800
  pb[i] = f2b(pos[(size_t)199 * 64 + i]);
}

// ---------------------------------------------------------------------------
// LayerNorm (fp32 in) -> bf16 out.  HAS_TIME: += time[r]*wt[c] + bt[c]
// ---------------------------------------------------------------------------
template <int HAS_TIME>
__global__ __launch_bounds__(256) void ln_kernel(
    const float* __restrict__ x, const float* __restrict__ g, const float* __restrict__ be,
    const float* __restrict__ tv, const float* __restrict__ wt, const float* __restrict__ bt,
    ushort* __restrict__ out) {
  int r = blockIdx.x, t = threadIdx.x;
  const float4* xr = (const float4*)(x + (size_t)r * H_DIM);
  float4 xv = xr[t];
  float s  = xv.x + xv.y + xv.z + xv.w;
  float s2 = xv.x * xv.x + xv.y * xv.y + xv.z * xv.z + xv.w * xv.w;
#pragma unroll
  for (int off = 32; off; off >>= 1) {
    s  += __shfl_xor(s, off);
    s2 += __shfl_xor(s2, off);
  }
  __shared__ float red[8];
  int lane = t & 63, wid = t >> 6;
  if (lane == 0) { red[wid] = s; red[4 + wid] = s2; }
  __syncthreads();
  float S  = red[0] + red[1] + red[2] + red[3];
  float S2 = red[4] + red[5] + red[6] + red[7];
  float m    = S * (1.0f / H_DIM);
  float var  = S2 * (1.0f / H_DIM) - m * m;
  float rstd = rsqrtf(var + 1e-5f);
  float tval = HAS_TIME ? tv[r] : 0.0f;
  float4 gv = ((const float4*)g)[t];
  float4 bv = ((const float4*)be)[t];
  float v0 = (xv.x - m) * rstd * gv.x + bv.x;
  float v1 = (xv.y - m) * rstd * gv.y + bv.y;
  float v2 = (xv.z - m) * rstd * gv.z + bv.z;
  float v3 = (xv.w - m) * rstd * gv.w + bv.w;
  if (HAS_TIME) {
    float4 wv = ((const float4*)wt)[t];
    float4 btv = ((const float4*)bt)[t];
    v0 += tval * wv.x + btv.x;
    v1 += tval * wv.y + btv.y;
    v2 += tval * wv.z + btv.z;
    v3 += tval * wv.w + btv.w;
  }
  ushort4 o;
  o.x = f2b(v0); o.y = f2b(v1); o.z = f2b(v2); o.w = f2b(v3);
  ((ushort4*)(out + (size_t)r * H_DIM))[t] = o;
}

// ---------------------------------------------------------------------------
// bf16 MFMA GEMM: C[M,N] = A[M,K] * Bt[N,K]^T + bias[N] (+epilogue)
// EPI 0: bf16 out.  EPI 1: exact GELU -> bf16.  EPI 2: +resid -> fp32 out
//   (safe when Cv == resid: per-thread read-then-write of same idx).
// 128x128 tile, BK=64 (two [128][32] LDS sub-planes so ds_read_b128 keeps the
// m97-verified 64B row stride; flat [128][64] would be 16-way bank conflicted).
// Staging via global_load_lds width=16.  256 thr, 4 waves 2x2.
// K%64==0, M%128==0, N%128==0 (guaranteed by our shapes).
// ---------------------------------------------------------------------------
template <int EPI>
__global__ __launch_bounds__(256) void gemm_bt(
    const ushort* __restrict__ A, const ushort* __restrict__ Bt,
    const float* __restrict__ bias, void* __restrict__ Cv,
    const float* __restrict__ resid, int M, int N, int K) {
  __shared__ __align__(16) ushort As[2 * 128 * 32];   // [kh][row][32]
  __shared__ __align__(16) ushort Bs[2 * 128 * 32];
  int t = threadIdx.x;
  int lane = t & 63, wave = t >> 6;
  int wm = wave >> 1, wn = wave & 1;
  int r15 = lane & 15, quad = lane >> 4;
  size_t row0 = (size_t)blockIdx.y * 128;
  size_t col0 = (size_t)blockIdx.x * 128;

  // staging: wave w covers rows w*32..w*32+31 of each 32-col sub-plane.
  // lane l -> row (l>>2), 16B chunk (l&3). LDS dest = base + lane*16 contig.
  int srow = (lane >> 2), scol = (lane & 3) * 8;
  const ushort* ga0 = A  + (row0 + wave * 32 +      srow) * K + scol;
  const ushort* ga1 = A  + (row0 + wave * 32 + 16 + srow) * K + scol;
  const ushort* gb0 = Bt + (col0 + wave * 32 +      srow) * K + scol;
  const ushort* gb1 = Bt + (col0 + wave * 32 + 16 + srow) * K + scol;
  ushort* la0 = As + (wave * 32) * 32;
  ushort* la1 = As + (wave * 32 + 16) * 32;
  ushort* lb0 = Bs + (wave * 32) * 32;
  ushort* lb1 = Bs + (wave * 32 + 16) * 32;

  f32x4 acc[4][4] = {};

  for (int k0 = 0; k0 < K; k0 += 64) {
#pragma unroll
    for (int kh = 0; kh < 2; ++kh) {
      int go = k0 + kh * 32, lo = kh * 4096;
      g2lds16(ga0 + go, la0 + lo);
      g2lds16(ga1 + go, la1 + lo);
      g2lds16(gb0 + go, lb0 + lo);
      g2lds16(gb1 + go, lb1 + lo);
    }
    __syncthreads();
#pragma unroll
    for (int kh = 0; kh < 2; ++kh) {
      bf16x8 af[4], bfr[4];
#pragma unroll
      for (int i = 0; i < 4; ++i)
        af[i] = *(const bf16x8*)&As[kh * 4096 + (wm * 64 + i * 16 + r15) * 32 + quad * 8];
#pragma unroll
      for (int j = 0; j < 4; ++j)
        bfr[j] = *(const bf16x8*)&Bs[kh * 4096 + (wn * 64 + j * 16 + r15) * 32 + quad * 8];
#pragma unroll
      for (int i = 0; i < 4; ++i)
#pragma unroll
        for (int j = 0; j < 4; ++j)
          acc[i][j] = __builtin_amdgcn_mfma_f32_16x16x32_bf16(af[i], bfr[j], acc[i][j], 0, 0, 0);
    }
    __syncthreads();
  }

  int mbase = (int)row0 + wm * 64;
  int nbase = (int)col0 + wn * 64;
#pragma unroll
  for (int i = 0; i < 4; ++i) {
#pragma unroll
    for (int j = 0; j < 4; ++j) {
      int col = nbase + j * 16 + r15;
      float bb = bias[col];
#pragma unroll
      for (int ii = 0; ii < 4; ++ii) {
        int row = mbase + i * 16 + quad * 4 + ii;
        size_t idx = (size_t)row * N + col;
        float v = acc[i][j][ii] + bb;
        if constexpr (EPI == 0) {
          ((ushort*)Cv)[idx] = f2b(v);
        } else if constexpr (EPI == 1) {
          float gl = 0.5f * v * (1.0f + erff(v * 0.70710678118f));
          ((ushort*)Cv)[idx] = f2b(gl);
        } else {
          ((float*)Cv)[idx] = v + resid[idx];
        }
      }
    }
  }
}

// ---------------------------------------------------------------------------
// MFMA attention.  One block (4 waves) per (b,h).
// scores = (Q@K^T)*0.125 + T[q, q-k],  T = Q@P^T  (P = pos_bf, rows d=q-k).
// ---------------------------------------------------------------------------
#define PW_STRIDE 228   // elems per row; 456B: 8B-aligned (b64 reads), ~4-way banks
__global__ __launch_bounds__(256) void attn_kernel(
    const ushort* __restrict__ qkv, const ushort* __restrict__ pos_bf,
    ushort* __restrict__ ctx) {
  int bh = blockIdx.x;
  int b = bh >> 4, h = bh & 15;
  __shared__ ushort Vt[64][PW_STRIDE];       // V^T: Vt[d][k]
  __shared__ ushort Pw[4][16][PW_STRIDE];    // per-wave: T strip, then exp(S)
  int t = threadIdx.x, lane = t & 63, wave = t >> 6;
  int r15 = lane & 15, quad = lane >> 4;
  const size_t base = ((size_t)b * S_LEN) * 3072 + (size_t)h * 64;

  // zero Vt pad cols 200..227
  for (int i = t; i < 64 * 28; i += 256) Vt[i / 28][200 + (i % 28)] = 0;
  // stage V transposed
  for (int i = t; i < 800; i += 256) {
    int kp = i >> 3, d0 = (i & 7) * 8;
    int k = kp * 2;
    union { uint4 v; ushort u[8]; } r0, r1;
    r0.v = *(const uint4*)&qkv[base + (size_t)k * 3072 + 2048 + d0];
    r1.v = *(const uint4*)&qkv[base + (size_t)(k + 1) * 3072 + 2048 + d0];
#pragma unroll
    for (int j = 0; j < 8; ++j) {
      ushort2 w2; w2.x = r0.u[j]; w2.y = r1.u[j];
      *(ushort2*)&Vt[d0 + j][k] = w2;
    }
  }
  __syncthreads();

  for (int qt = wave; qt < 13; qt += 4) {
    int q0 = qt * 16;
    int qrow = q0 + r15; if (qrow > 199) qrow = 199;
    const ushort* qp = qkv + base + (size_t)qrow * 3072;
    bf16x8 aq0 = ld_g16(qp + quad * 8);
    bf16x8 aq1 = ld_g16(qp + 32 + quad * 8);
    ushort* pw = &Pw[wave][0][0];

    // ---- Phase 1: T strip = Q @ P^T ----
#pragma unroll
    for (int dt = 0; dt < 13; ++dt) {
      if (dt > qt) continue;
      int prow = dt * 16 + r15; if (prow > 199) prow = 199;
      const ushort* pp = pos_bf + (size_t)prow * 64;
      bf16x8 p0 = ld_g16(pp + quad * 8);
      bf16x8 p1 = ld_g16(pp + 32 + quad * 8);
      f32x4 tt = {};
      tt = __builtin_amdgcn_mfma_f32_16x16x32_bf16(aq0, p0, tt, 0, 0, 0);
      tt = __builtin_amdgcn_mfma_f32_16x16x32_bf16(aq1, p1, tt, 0, 0, 0);
#pragma unroll
      for (int ii = 0; ii < 4; ++ii)
        pw[(quad * 4 + ii) * PW_STRIDE + dt * 16 + r15] = f2b(tt[ii]);
    }

    // ---- Phase 2: scores ----
    f32x4 sreg[13];
    float rowmax[4] = {-3.0e38f, -3.0e38f, -3.0e38f, -3.0e38f};
#pragma unroll
    for (int kt = 0; kt < 13; ++kt) {
      if (kt > qt) continue;
      int krow = kt * 16 + r15; if (krow > 199) krow = 199;
      const ushort* kp = qkv + base + (size_t)krow * 3072 + 1024;
      bf16x8 k0 = ld_g16(kp + quad * 8);
      bf16x8 k1 = ld_g16(kp + 32 + quad * 8);
      f32x4 s = {};
      s = __builtin_amdgcn_mfma_f32_16x16x32_bf16(aq0, k0, s, 0, 0, 0);
      s = __builtin_amdgcn_mfma_f32_16x16x32_bf16(aq1, k1, s, 0, 0, 0);
      int k = kt * 16 + r15;
#pragma unroll
      for (int ii = 0; ii < 4; ++ii) {
        int q = q0 + quad * 4 + ii;
        float v;
        if (k <= q) {
          v = s[ii] * 0.125f + b2f(pw[(quad * 4 + ii) * PW_STRIDE + (q - k)]);
        } else {
          v = -1.0e30f;
        }
        s[ii] = v;
        rowmax[ii] = fmaxf(rowmax[ii], v);
      }
      sreg[kt] = s;
    }
#pragma unroll
    for (int off = 8; off; off >>= 1)
#pragma unroll
      for (int ii = 0; ii < 4; ++ii)
        rowmax[ii] = fmaxf(rowmax[ii], __shfl_xor(rowmax[ii], off));

    float rsum[4] = {0.f, 0.f, 0.f, 0.f};
#pragma unroll
    for (int kt = 0; kt < 13; ++kt) {
      if (kt > qt) continue;
#pragma unroll
      for (int ii = 0; ii < 4; ++ii) {
        float e = __expf(sreg[kt][ii] - rowmax[ii]);
        rsum[ii] += e;
        pw[(quad * 4 + ii) * PW_STRIDE + kt * 16 + r15] = f2b(e);
      }
    }
    if ((qt & 1) == 0) {
#pragma unroll
      for (int ii = 0; ii < 4; ++ii)
        pw[(quad * 4 + ii) * PW_STRIDE + (qt + 1) * 16 + r15] = 0;
    }
#pragma unroll
    for (int off = 8; off; off >>= 1)
#pragma unroll
      for (int ii = 0; ii < 4; ++ii)
        rsum[ii] += __shfl_xor(rsum[ii], off);
    float rinv[4];
#pragma unroll
    for (int ii = 0; ii < 4; ++ii) rinv[ii] = 1.0f / rsum[ii];

    // ---- Phase 3: ctx = exp(S) @ V ----
    int nk = (q0 + 15) / 32 + 1;
    f32x4 acc[4] = {};
#pragma unroll
    for (int k32 = 0; k32 < 7; ++k32) {
      if (k32 >= nk) continue;
      bf16x8 ap = ld_lds8x2(&pw[r15 * PW_STRIDE + k32 * 32 + quad * 8]);
#pragma unroll
      for (int n = 0; n < 4; ++n) {
        bf16x8 bv = ld_lds8x2(&Vt[n * 16 + r15][k32 * 32 + quad * 8]);
        acc[n] = __builtin_amdgcn_mfma_f32_16x16x32_bf16(ap, bv, acc[n], 0, 0, 0);
      }
    }
#pragma unroll
    for (int n = 0; n < 4; ++n)
#pragma unroll
      for (int ii = 0; ii < 4; ++ii) {
        int q = q0 + quad * 4 + ii;
        if (q < S_LEN)
          ctx[((size_t)(b * S_LEN + q)) * H_DIM + h * 64 + n * 16 + r15] =
              f2b(acc[n][ii] * rinv[ii]);
      }
  }
}

// ---------------------------------------------------------------------------
// Launcher.  Workspace layout (aliased; peak ~124 MB):
//   [weights bf16^T: 25.2 MB][pos_bf 25.6KB][qkv 78.6 MB -> h2+gelu chunk]
//   [hbf 26.2 MB -> ctx]          res2 lives in d_out (fp32, 52.4 MB).
// ---------------------------------------------------------------------------
extern "C" void kernel_launch(void* const* d_in, const int* in_sizes, int n_in,
                              void* d_out, int out_size, void* d_ws, size_t ws_size,
                              hipStream_t stream) {
  (void)in_sizes; (void)n_in; (void)out_size; (void)ws_size;
  const float* x    = (const float*)d_in[0];
  const float* timev= (const float*)d_in[1];
  const float* wq   = (const float*)d_in[2];
  const float* bq   = (const float*)d_in[3];
  const float* wk   = (const float*)d_in[4];
  const float* bk   = (const float*)d_in[5];
  const float* wv   = (const float*)d_in[6];
  const float* bv   = (const float*)d_in[7];
  const float* wo   = (const float*)d_in[8];
  const float* bo   = (const float*)d_in[9];
  const float* wt   = (const float*)d_in[10];
  const float* bt   = (const float*)d_in[11];
  const float* pos  = (const float*)d_in[12];
  const float* g1   = (const float*)d_in[13];
  const float* be1  = (const float*)d_in[14];
  const float* g2   = (const float*)d_in[15];
  const float* be2  = (const float*)d_in[16];
  const float* w1   = (const float*)d_in[17];
  const float* bf1  = (const float*)d_in[18];
  const float* w2   = (const float*)d_in[19];
  const float* bf2  = (const float*)d_in[20];

  char* ws = (char*)d_ws;
  ushort* wqkv_t = (ushort*)ws;   ws += (size_t)3072 * 1024 * 2;   //  6.29 MB
  ushort* wo_t   = (ushort*)ws;   ws += (size_t)1024 * 1024 * 2;   //  2.10 MB
  ushort* w1_t   = (ushort*)ws;   ws += (size_t)4096 * 1024 * 2;   //  8.39 MB
  ushort* w2_t   = (ushort*)ws;   ws += (size_t)1024 * 4096 * 2;   //  8.39 MB
  float*  bqkv   = (float*)ws;    ws += (size_t)16384;             //  16 KB
  ushort* pos_bf = (ushort*)ws;   ws += (size_t)200 * 64 * 2;      //  25.6 KB
  // region R1: qkv during attention; afterwards h2 + gelu chunk
  char* r1 = ws;                  ws += (size_t)NROWS * 3072 * 2;  // 78.64 MB
  ushort* qkv  = (ushort*)r1;
  ushort* h2   = (ushort*)r1;                                      // 26.21 MB
  ushort* gbuf = (ushort*)(r1 + (size_t)NROWS * H_DIM * 2);        // 52.43 MB
  // region R2: hbf, then ctx
  char* r2 = ws;                  ws += (size_t)NROWS * 1024 * 2;  // 26.21 MB
  ushort* hbf = (ushort*)r2;
  ushort* ctx = (ushort*)r2;
  float* res2 = (float*)d_out;

  dim3 tb(32, 8);
  transpose_to_bf16<<<dim3(32, 32), tb, 0, stream>>>(wq, wqkv_t,                 1024, 1024);
  transpose_to_bf16<<<dim3(32, 32), tb, 0, stream>>>(wk, wqkv_t + 1024 * 1024,   1024, 1024);
  transpose_to_bf16<<<dim3(32, 32), tb, 0, stream>>>(wv, wqkv_t + 2048 * 1024,   1024, 1024);
  transpose_to_bf16<<<dim3(32, 32), tb, 0, stream>>>(wo, wo_t,                   1024, 1024);
  transpose_to_bf16<<<dim3(128, 32), tb, 0, stream>>>(w1, w1_t,                  1024, 4096);
  transpose_to_bf16<<<dim3(32, 128), tb, 0, stream>>>(w2, w2_t,                  4096, 1024);
  concat_bias<<<12, 256, 0, stream>>>(bq, bk, bv, bqkv);
  pos_to_bf16<<<50, 256, 0, stream>>>(pos, pos_bf);

  // LN1 + time embed -> hbf (bf16)
  ln_kernel<1><<<NROWS, 256, 0, stream>>>(x, g1, be1, timev, wt, bt, hbf);

  // fused QKV GEMM: [12800,1024] x [3072,1024]^T -> qkv bf16
  gemm_bt<0><<<dim3(24, 100), 256, 0, stream>>>(hbf, wqkv_t, bqkv, qkv, nullptr,
                                                NROWS, 3072, 1024);
  // MFMA attention: qkv -> ctx (overwrites hbf region; hbf is dead now)
  attn_kernel<<<B_SZ * NHEAD, 256, 0, stream>>>(qkv, pos_bf, ctx);

  // out = ctx @ wo + bo + x   (fp32, into d_out as res2)
  gemm_bt<2><<<dim3(8, 100), 256, 0, stream>>>(ctx, wo_t, bo, res2, x,
                                               NROWS, 1024, 1024);
  // LN2 -> h2 (bf16, overwrites qkv region; qkv is dead now)
  ln_kernel<0><<<NROWS, 256, 0, stream>>>(res2, g2, be2, nullptr, nullptr, nullptr, h2);

  // FF in 2 row-chunks of 6400 (gelu buffer fits in the freed qkv region)
  for (int c = 0; c < 2; ++c) {
    size_t ro = (size_t)c * 6400;
    gemm_bt<1><<<dim3(32, 50), 256, 0, stream>>>(h2 + ro * 1024, w1_t, bf1, gbuf, nullptr,
                                                 6400, 4096, 1024);
    gemm_bt<2><<<dim3(8, 50), 256, 0, stream>>>(gbuf, w2_t, bf2, (float*)d_out + ro * 1024,
                                                res2 + ro * 1024, 6400, 1024, 4096);
  }
}